// Round 7
// baseline (231.590 us; speedup 1.0000x reference)
//
#include <hip/hip_runtime.h>
#include <hip/hip_bf16.h>
#include <stdint.h>

#define S_ATOMS 25
#define DIM 64
#define AP 40      // hT row stride (shorts): 80B rows
#define VP 72      // v' row stride (shorts): 144B rows
#define BWAVES 8   // waves per block (512 threads)
#define XB2 2560   // shorts per wave buffer: max(64*AP, 32*VP) = 2560 (5120B)

typedef __attribute__((ext_vector_type(8))) short short8;   // 8 bf16
typedef __attribute__((ext_vector_type(4))) short short4s;  // 4 bf16 (b64)
typedef __attribute__((ext_vector_type(4))) float f32x4;

static __device__ __forceinline__ short bf(float x) {
    return (short)__builtin_bit_cast(unsigned short, __float2bfloat16(x));
}

// ---------------- phase A: W-pack + emb->bf16 + edge histogram --------------
// byteMode: hist byte index n = mol*800 + dl*32 + sl  (row stride 32, pad=0)
// nibble  : hist nibble index n = mol*625 + dl*25 + sl
__global__ __launch_bounds__(256) void phaseA_k(
    const float* __restrict__ W_fp, const float* __restrict__ emb,
    const int* __restrict__ esrc, const int* __restrict__ edst,
    unsigned* __restrict__ Bg, short* __restrict__ wpk, short* __restrict__ embT,
    int LH, int E, int NF, int byteMode)
{
    int gid = blockIdx.x * 256 + threadIdx.x;
    if (gid < LH * 512) {             // prepack W_fp MFMA B-fragments
        int t = gid;
        int layer = t >> 9, q = t & 511;
        int nt = q >> 7, ks = (q >> 6) & 1, lane = q & 63;
        int cc = lane & 15, gg = lane >> 4;
        const float* p = W_fp + (size_t)layer * 4096 + (nt * 16 + cc) * 64 + ks * 32 + 8 * gg;
        short8 s;
        #pragma unroll
        for (int j = 0; j < 8; ++j) s[j] = bf(p[j]);
        *(short8*)(wpk + (size_t)t * 8) = s;
    }
    if (byteMode && gid < NF * 8) {   // emb f32 -> bf16 row-major
        int row = gid >> 3, seg = gid & 7;
        const float* p = emb + (size_t)row * DIM + seg * 8;
        short8 s;
        #pragma unroll
        for (int j = 0; j < 8; ++j) s[j] = bf(p[j]);
        *(short8*)(embT + (size_t)row * DIM + seg * 8) = s;
    }
    if (gid < E) {                    // adjacency histogram
        int s = esrc[gid], d = edst[gid];
        int m  = s / S_ATOMS;
        int sl = s - m * S_ATOMS;
        int dl = d - m * S_ATOMS;
        if (byteMode) {
            int n = m * 800 + dl * 32 + sl;          // byte index
            atomicAdd(&Bg[n >> 2], 1u << ((n & 3) * 8));
        } else {
            int n = m * 625 + dl * 25 + sl;          // nibble index
            atomicAdd(&Bg[n >> 3], 1u << ((n & 7) * 4));
        }
    }
}

// ---------------- fused per-molecule GNN: 1 mol per wave, 8 waves/block -----
// GEMM1: h[atom][dout] = v*W^T (A=v, B=Wpack)       -> 16 MFMA
// GEMM2: u^T[dim][atom] = h^T * B^T = mfma(b2,amat) -> 8 MFMA,  B = I + A
template<bool FAST>
__global__ __launch_bounds__(512, 8) void gnn_k(
    const float* __restrict__ emb,     // [NF,64] f32 (fallback path)
    const short* __restrict__ embT,    // [NF,64] bf16 (fast path)
    const float* __restrict__ b_fp,    // [LH,64]
    const float* __restrict__ W_out,   // [LO,64,64]
    const float* __restrict__ b_out,   // [LO,64]
    const float* __restrict__ W_prop,  // [1,64]
    const float* __restrict__ b_prop,  // [1]
    const int*   __restrict__ fps,     // [T]
    const unsigned* __restrict__ Bg,   // adjacency counts (byte or nibble)
    const short* __restrict__ wpk,     // prepacked W frags
    float* __restrict__ out,           // [M]
    int LH, int LO, int M)
{
    __shared__ __align__(16) short xb_all[BWAVES][XB2];   // 40960 B total
    const int w = threadIdx.x >> 6, l = threadIdx.x & 63;
    const int c = l & 15, g = l >> 4;
    short* xb = xb_all[w];
    float* mv = (float*)xb;            // 64-float mol vector overlays xb
    const short8* wp8 = (const short8*)wpk;

    const int mol = blockIdx.x * BWAVES + w;
    if (mol >= M) return;              // wave-uniform

    // ---- amat: B^T-operand frags, B = I + A ----
    short8 amat[2];
    #pragma unroll
    for (int at = 0; at < 2; ++at) {
        int row = at * 16 + c;
        float f[8];
        if (row < S_ATOMS) {
            if (FAST) {
                // bytes [mol*800 + row*32 + 8g .. +7]: two aligned u32 words
                int w0 = mol * 200 + row * 8 + g * 2;
                unsigned u0 = Bg[w0], u1 = Bg[w0 + 1];
                #pragma unroll
                for (int j = 0; j < 8; ++j) {
                    unsigned u = (j < 4) ? u0 : u1;
                    float fj = (float)((u >> (8 * (j & 3))) & 0xffu);  // cvt_f32_ubyte
                    if (8 * g + j == row) fj += 1.0f;                  // +I
                    f[j] = fj;   // pad cols 25..31 are never incremented -> 0
                }
            } else {
                int n0 = mol * 625 + row * 25 + 8 * g;
                unsigned lo = Bg[n0 >> 3], hi = Bg[(n0 >> 3) + 1];
                unsigned long long v64 = ((unsigned long long)hi << 32) | lo;
                v64 >>= ((n0 & 7) * 4);
                #pragma unroll
                for (int j = 0; j < 8; ++j) {
                    unsigned n = (unsigned)(v64 >> (4 * j)) & 0xFu;
                    f[j] = (8 * g + j) < S_ATOMS ? (float)n : 0.f;
                    if (8 * g + j == row) f[j] += 1.0f;
                }
            }
        } else {
            #pragma unroll
            for (int j = 0; j < 8; ++j) f[j] = 0.f;
        }
        short8 s;
        #pragma unroll
        for (int j = 0; j < 8; ++j) s[j] = bf(f[j]);
        amat[at] = s;
    }

    // ---- layer-0 A-frags from the embedding table ----
    short8 a1[2][2];
    #pragma unroll
    for (int mt = 0; mt < 2; ++mt) {
        int atom = mt * 16 + c;
        int aa = atom < S_ATOMS ? atom : S_ATOMS - 1;   // pads killed by B cols=0
        int fi = fps[mol * S_ATOMS + aa];
        #pragma unroll
        for (int ks = 0; ks < 2; ++ks) {
            if (FAST) {
                a1[mt][ks] = *(const short8*)(embT + (size_t)fi * DIM + ks * 32 + 8 * g);
            } else {
                const float4* qp = (const float4*)(emb + (size_t)fi * DIM + ks * 32 + 8 * g);
                float4 f0 = qp[0], f1 = qp[1];
                short8 s;
                s[0]=bf(f0.x); s[1]=bf(f0.y); s[2]=bf(f0.z); s[3]=bf(f0.w);
                s[4]=bf(f1.x); s[5]=bf(f1.y); s[6]=bf(f1.z); s[7]=bf(f1.w);
                a1[mt][ks] = s;
            }
        }
    }

    for (int layer = 0; layer < LH; ++layer) {
        // ---- GEMM1: acc = v*W^T + b ----
        float bv[4];
        #pragma unroll
        for (int nt = 0; nt < 4; ++nt) bv[nt] = b_fp[layer * DIM + nt * 16 + c];
        f32x4 acc[2][4];
        #pragma unroll
        for (int mt = 0; mt < 2; ++mt)
            #pragma unroll
            for (int nt = 0; nt < 4; ++nt) {
                f32x4 a; a[0]=bv[nt]; a[1]=bv[nt]; a[2]=bv[nt]; a[3]=bv[nt];
                acc[mt][nt] = a;
            }
        #pragma unroll
        for (int ks = 0; ks < 2; ++ks) {
            short8 bwk[4];
            #pragma unroll
            for (int nt = 0; nt < 4; ++nt)
                bwk[nt] = wp8[layer * 512 + nt * 128 + ks * 64 + l];
            #pragma unroll
            for (int mt = 0; mt < 2; ++mt)
                #pragma unroll
                for (int nt = 0; nt < 4; ++nt)
                    acc[mt][nt] = __builtin_amdgcn_mfma_f32_16x16x32_bf16(
                        a1[mt][ks], bwk[nt], acc[mt][nt], 0, 0, 0);
        }

        // ---- epilogue1: relu, pack, write hT[dout][atom] ----
        #pragma unroll
        for (int mt = 0; mt < 2; ++mt)
            #pragma unroll
            for (int nt = 0; nt < 4; ++nt) {
                short4s p;
                p[0] = bf(fmaxf(acc[mt][nt][0], 0.f));
                p[1] = bf(fmaxf(acc[mt][nt][1], 0.f));
                p[2] = bf(fmaxf(acc[mt][nt][2], 0.f));
                p[3] = bf(fmaxf(acc[mt][nt][3], 0.f));
                *(short4s*)&xb[(nt * 16 + c) * AP + mt * 16 + 4 * g] = p;
            }
        __builtin_amdgcn_wave_barrier();

        // ---- GEMM2: u^T = h^T * B^T ----
        short8 b2[4];
        #pragma unroll
        for (int dt = 0; dt < 4; ++dt)
            b2[dt] = *(const short8*)&xb[(dt * 16 + c) * AP + 8 * g];
        f32x4 ua[4][2];
        #pragma unroll
        for (int dt = 0; dt < 4; ++dt)
            #pragma unroll
            for (int at = 0; at < 2; ++at) {
                f32x4 z; z[0]=0.f; z[1]=0.f; z[2]=0.f; z[3]=0.f;
                ua[dt][at] = __builtin_amdgcn_mfma_f32_16x16x32_bf16(
                    b2[dt], amat[at], z, 0, 0, 0);
            }

        // ---- per-atom norms (atom = at*16+c; reduce over g-groups) ----
        float ss0 = 0.f, ss1 = 0.f;
        #pragma unroll
        for (int dt = 0; dt < 4; ++dt)
            #pragma unroll
            for (int r = 0; r < 4; ++r) {
                ss0 += ua[dt][0][r] * ua[dt][0][r];
                ss1 += ua[dt][1][r] * ua[dt][1][r];
            }
        ss0 += __shfl_xor(ss0, 16); ss0 += __shfl_xor(ss0, 32);
        ss1 += __shfl_xor(ss1, 16); ss1 += __shfl_xor(ss1, 32);
        float rn0 = __builtin_amdgcn_rsqf(fmaxf(ss0, 1e-24f));
        float rn1 = __builtin_amdgcn_rsqf(fmaxf(ss1, 1e-24f));
        __builtin_amdgcn_wave_barrier();

        if (layer != LH - 1) {
            // ---- v' -> xb[atom][dim] (b2 already consumed into regs) ----
            #pragma unroll
            for (int at = 0; at < 2; ++at) {
                float r0 = at ? rn1 : rn0;
                #pragma unroll
                for (int dt = 0; dt < 4; ++dt) {
                    short4s p;
                    p[0] = bf(ua[dt][at][0] * r0);
                    p[1] = bf(ua[dt][at][1] * r0);
                    p[2] = bf(ua[dt][at][2] * r0);
                    p[3] = bf(ua[dt][at][3] * r0);
                    *(short4s*)&xb[(at * 16 + c) * VP + dt * 16 + 4 * g] = p;
                }
            }
            __builtin_amdgcn_wave_barrier();
            #pragma unroll
            for (int mt = 0; mt < 2; ++mt)
                #pragma unroll
                for (int ks = 0; ks < 2; ++ks)
                    a1[mt][ks] = *(const short8*)&xb[(mt * 16 + c) * VP + ks * 32 + 8 * g];
        } else {
            // ---- molecule sum via 15-shfl split-butterfly over c-lanes ----
            float mx[16];
            #pragma unroll
            for (int dt = 0; dt < 4; ++dt)
                #pragma unroll
                for (int r = 0; r < 4; ++r)
                    mx[dt * 4 + r] = ua[dt][0][r] * rn0 + ua[dt][1][r] * rn1;
            #pragma unroll
            for (int k = 0; k < 8; ++k) {
                float send = (c & 8) ? mx[k] : mx[k + 8];
                float keep = (c & 8) ? mx[k + 8] : mx[k];
                mx[k] = keep + __shfl_xor(send, 8);
            }
            #pragma unroll
            for (int k = 0; k < 4; ++k) {
                float send = (c & 4) ? mx[k] : mx[k + 4];
                float keep = (c & 4) ? mx[k + 4] : mx[k];
                mx[k] = keep + __shfl_xor(send, 4);
            }
            #pragma unroll
            for (int k = 0; k < 2; ++k) {
                float send = (c & 2) ? mx[k] : mx[k + 2];
                float keep = (c & 2) ? mx[k + 2] : mx[k];
                mx[k] = keep + __shfl_xor(send, 2);
            }
            {
                float send = (c & 1) ? mx[0] : mx[1];
                float keep = (c & 1) ? mx[1] : mx[0];
                mx[0] = keep + __shfl_xor(send, 1);
            }
            int dim = (c >> 2) * 16 + 4 * g + (c & 3);
            mv[dim] = mx[0];                 // overlays hT region (done with it)
            __builtin_amdgcn_wave_barrier();
        }
    }

    // ---- output MLP (lane = dout), W_out rows L2-hot ----
    float cur = 0.f;
    for (int layer = 0; layer < LO; ++layer) {
        const float4* wr = (const float4*)(W_out + ((size_t)layer * DIM + l) * DIM);
        const float4* mv4 = (const float4*)mv;
        float accv = b_out[layer * DIM + l];
        #pragma unroll
        for (int k = 0; k < 16; ++k) {
            float4 vv = mv4[k]; float4 ww = wr[k];
            accv += vv.x * ww.x + vv.y * ww.y + vv.z * ww.z + vv.w * ww.w;
        }
        __builtin_amdgcn_wave_barrier();
        cur = fmaxf(accv, 0.f);
        mv[l] = cur;
        __builtin_amdgcn_wave_barrier();
    }
    float p = cur * W_prop[l];
    #pragma unroll
    for (int o = 32; o; o >>= 1) p += __shfl_xor(p, o);
    if (l == 0) out[mol] = p + b_prop[0];
}

// ---------------- launch ----------------------------------------------------
extern "C" void kernel_launch(void* const* d_in, const int* in_sizes, int n_in,
                              void* d_out, int out_size, void* d_ws, size_t ws_size,
                              hipStream_t stream)
{
    const float* emb    = (const float*)d_in[0];
    const float* W_fp   = (const float*)d_in[1];
    const float* b_fp   = (const float*)d_in[2];
    const float* W_out  = (const float*)d_in[3];
    const float* b_out  = (const float*)d_in[4];
    const float* W_prop = (const float*)d_in[5];
    const float* b_prop = (const float*)d_in[6];
    const int*   fps    = (const int*)d_in[7];
    const int*   esrc   = (const int*)d_in[8];
    const int*   edst   = (const int*)d_in[9];

    const int T  = in_sizes[7];
    const int E  = in_sizes[8];
    const int NF = in_sizes[0] / DIM;
    const int LH = in_sizes[1] / (DIM * DIM);
    const int LO = in_sizes[3] / (DIM * DIM);
    const int M  = T / S_ATOMS;

    // fast layout: [byte hist M*800 | embT bf16 | wpk]; fallback: [nibble hist | wpk]
    size_t hist_fast = (size_t)M * 800;
    size_t embT_b    = (size_t)NF * DIM * 2;
    size_t wpk_b     = (size_t)LH * 512 * 16;
    size_t need_fast = hist_fast + 256 + embT_b + 256 + wpk_b + 4096;
    bool fast = ws_size >= need_fast;

    unsigned* Bg; short* embT; short* wpk; size_t hist_bytes;
    if (fast) {
        hist_bytes = hist_fast;
        Bg   = (unsigned*)d_ws;
        embT = (short*)((char*)d_ws + hist_fast + 256);
        wpk  = (short*)((char*)d_ws + hist_fast + 256 + embT_b + 256);
    } else {
        hist_bytes = ((size_t)M * 625 + 1) / 2;
        Bg   = (unsigned*)d_ws;
        embT = nullptr;
        wpk  = (short*)((char*)d_ws + ((hist_bytes + 255) & ~(size_t)255) + 256);
    }

    hipMemsetAsync(Bg, 0, hist_bytes + 16, stream);

    int workA = E; if (NF * 8 > workA) workA = NF * 8; if (LH * 512 > workA) workA = LH * 512;
    phaseA_k<<<(workA + 255) / 256, 256, 0, stream>>>(
        W_fp, emb, esrc, edst, Bg, wpk, embT, LH, E, NF, fast ? 1 : 0);

    int grid = (M + BWAVES - 1) / BWAVES;
    if (fast)
        gnn_k<true><<<grid, BWAVES * 64, 0, stream>>>(emb, embT, b_fp, W_out, b_out,
            W_prop, b_prop, fps, Bg, wpk, (float*)d_out, LH, LO, M);
    else
        gnn_k<false><<<grid, BWAVES * 64, 0, stream>>>(emb, embT, b_fp, W_out, b_out,
            W_prop, b_prop, fps, Bg, wpk, (float*)d_out, LH, LO, M);
}

// Round 8
// 193.985 us; speedup vs baseline: 1.1939x; 1.1939x over previous
//
#include <hip/hip_runtime.h>
#include <hip/hip_bf16.h>
#include <stdint.h>

#define S_ATOMS 25
#define DIM 64
#define AP 40      // hT row stride (shorts): 80B rows
#define VP 72      // v' row stride (shorts): 144B rows
#define BWAVES 8   // waves per block (512 threads)
#define PM 2       // molecules per wave (sequential, 1 live at a time)
#define XB2 2560   // shorts per wave buffer: max(64*AP, 32*VP) = 2560 (5120B)

typedef __attribute__((ext_vector_type(8))) short short8;   // 8 bf16
typedef __attribute__((ext_vector_type(4))) short short4s;  // 4 bf16 (b64)
typedef __attribute__((ext_vector_type(4))) float f32x4;

static __device__ __forceinline__ short bf(float x) {
    return (short)__builtin_bit_cast(unsigned short, __float2bfloat16(x));
}

// ---------------- phase A: W-pack + emb->bf16 + edge histogram --------------
// byteMode: hist byte index n = mol*800 + dl*32 + sl  (row stride 32, pad=0)
// nibble  : hist nibble index n = mol*625 + dl*25 + sl
__global__ __launch_bounds__(256) void phaseA_k(
    const float* __restrict__ W_fp, const float* __restrict__ emb,
    const int* __restrict__ esrc, const int* __restrict__ edst,
    unsigned* __restrict__ Bg, short* __restrict__ wpk, short* __restrict__ embT,
    int LH, int E, int NF, int byteMode)
{
    int gid = blockIdx.x * 256 + threadIdx.x;
    if (gid < LH * 512) {             // prepack W_fp MFMA B-fragments
        int t = gid;
        int layer = t >> 9, q = t & 511;
        int nt = q >> 7, ks = (q >> 6) & 1, lane = q & 63;
        int cc = lane & 15, gg = lane >> 4;
        const float* p = W_fp + (size_t)layer * 4096 + (nt * 16 + cc) * 64 + ks * 32 + 8 * gg;
        short8 s;
        #pragma unroll
        for (int j = 0; j < 8; ++j) s[j] = bf(p[j]);
        *(short8*)(wpk + (size_t)t * 8) = s;
    }
    if (byteMode && gid < NF * 8) {   // emb f32 -> bf16 row-major
        int row = gid >> 3, seg = gid & 7;
        const float* p = emb + (size_t)row * DIM + seg * 8;
        short8 s;
        #pragma unroll
        for (int j = 0; j < 8; ++j) s[j] = bf(p[j]);
        *(short8*)(embT + (size_t)row * DIM + seg * 8) = s;
    }
    if (gid < E) {                    // adjacency histogram
        int s = esrc[gid], d = edst[gid];
        int m  = s / S_ATOMS;
        int sl = s - m * S_ATOMS;
        int dl = d - m * S_ATOMS;
        if (byteMode) {
            int n = m * 800 + dl * 32 + sl;          // byte index
            atomicAdd(&Bg[n >> 2], 1u << ((n & 3) * 8));
        } else {
            int n = m * 625 + dl * 25 + sl;          // nibble index
            atomicAdd(&Bg[n >> 3], 1u << ((n & 7) * 4));
        }
    }
}

// ---------------- fused per-molecule GNN: 8 waves/block, PM mols per wave ---
// GEMM1: h[atom][dout] = v*W^T (A=v, B=Wpack)       -> 16 MFMA
// GEMM2: u^T[dim][atom] = h^T * B^T = mfma(b2,amat) -> 8 MFMA,  B = I + A
template<bool FAST>
__global__ __launch_bounds__(512, 4) void gnn_k(
    const float* __restrict__ emb,     // [NF,64] f32 (fallback path)
    const short* __restrict__ embT,    // [NF,64] bf16 (fast path)
    const float* __restrict__ b_fp,    // [LH,64]
    const float* __restrict__ W_out,   // [LO,64,64]
    const float* __restrict__ b_out,   // [LO,64]
    const float* __restrict__ W_prop,  // [1,64]
    const float* __restrict__ b_prop,  // [1]
    const int*   __restrict__ fps,     // [T]
    const unsigned* __restrict__ Bg,   // adjacency counts (byte or nibble)
    const short* __restrict__ wpk,     // prepacked W frags
    float* __restrict__ out,           // [M]
    int LH, int LO, int M)
{
    __shared__ __align__(16) short xb_all[BWAVES][XB2];   // 40960 B total
    const int w = threadIdx.x >> 6, l = threadIdx.x & 63;
    const int c = l & 15, g = l >> 4;
    short* xb = xb_all[w];
    float* mv = (float*)xb;            // 64-float mol vector overlays xb
    const short8* wp8 = (const short8*)wpk;

    for (int mi = 0; mi < PM; ++mi) {
        const int mol = (blockIdx.x * BWAVES + w) * PM + mi;
        if (mol >= M) break;           // wave-uniform

        // ---- amat: B^T-operand frags, B = I + A ----
        short8 amat[2];
        #pragma unroll
        for (int at = 0; at < 2; ++at) {
            int row = at * 16 + c;
            float f[8];
            if (row < S_ATOMS) {
                if (FAST) {
                    // bytes [mol*800 + row*32 + 8g .. +7]: two aligned u32 words
                    int w0 = mol * 200 + row * 8 + g * 2;
                    unsigned u0 = Bg[w0], u1 = Bg[w0 + 1];
                    #pragma unroll
                    for (int j = 0; j < 8; ++j) {
                        unsigned u = (j < 4) ? u0 : u1;
                        float fj = (float)((u >> (8 * (j & 3))) & 0xffu);
                        if (8 * g + j == row) fj += 1.0f;              // +I
                        f[j] = fj;   // pad cols 25..31 never incremented -> 0
                    }
                } else {
                    int n0 = mol * 625 + row * 25 + 8 * g;
                    unsigned lo = Bg[n0 >> 3], hi = Bg[(n0 >> 3) + 1];
                    unsigned long long v64 = ((unsigned long long)hi << 32) | lo;
                    v64 >>= ((n0 & 7) * 4);
                    #pragma unroll
                    for (int j = 0; j < 8; ++j) {
                        unsigned n = (unsigned)(v64 >> (4 * j)) & 0xFu;
                        f[j] = (8 * g + j) < S_ATOMS ? (float)n : 0.f;
                        if (8 * g + j == row) f[j] += 1.0f;
                    }
                }
            } else {
                #pragma unroll
                for (int j = 0; j < 8; ++j) f[j] = 0.f;
            }
            short8 s;
            #pragma unroll
            for (int j = 0; j < 8; ++j) s[j] = bf(f[j]);
            amat[at] = s;
        }

        // ---- layer-0 A-frags from the embedding table ----
        short8 a1[2][2];
        #pragma unroll
        for (int mt = 0; mt < 2; ++mt) {
            int atom = mt * 16 + c;
            int aa = atom < S_ATOMS ? atom : S_ATOMS - 1;  // pads killed by B cols=0
            int fi = fps[mol * S_ATOMS + aa];
            #pragma unroll
            for (int ks = 0; ks < 2; ++ks) {
                if (FAST) {
                    a1[mt][ks] = *(const short8*)(embT + (size_t)fi * DIM + ks * 32 + 8 * g);
                } else {
                    const float4* qp = (const float4*)(emb + (size_t)fi * DIM + ks * 32 + 8 * g);
                    float4 f0 = qp[0], f1 = qp[1];
                    short8 s;
                    s[0]=bf(f0.x); s[1]=bf(f0.y); s[2]=bf(f0.z); s[3]=bf(f0.w);
                    s[4]=bf(f1.x); s[5]=bf(f1.y); s[6]=bf(f1.z); s[7]=bf(f1.w);
                    a1[mt][ks] = s;
                }
            }
        }

        for (int layer = 0; layer < LH; ++layer) {
            // ---- GEMM1: acc = v*W^T + b ----
            float bv[4];
            #pragma unroll
            for (int nt = 0; nt < 4; ++nt) bv[nt] = b_fp[layer * DIM + nt * 16 + c];
            f32x4 acc[2][4];
            #pragma unroll
            for (int mt = 0; mt < 2; ++mt)
                #pragma unroll
                for (int nt = 0; nt < 4; ++nt) {
                    f32x4 a; a[0]=bv[nt]; a[1]=bv[nt]; a[2]=bv[nt]; a[3]=bv[nt];
                    acc[mt][nt] = a;
                }
            #pragma unroll
            for (int ks = 0; ks < 2; ++ks) {
                short8 bwk[4];
                #pragma unroll
                for (int nt = 0; nt < 4; ++nt)
                    bwk[nt] = wp8[layer * 512 + nt * 128 + ks * 64 + l];
                #pragma unroll
                for (int mt = 0; mt < 2; ++mt)
                    #pragma unroll
                    for (int nt = 0; nt < 4; ++nt)
                        acc[mt][nt] = __builtin_amdgcn_mfma_f32_16x16x32_bf16(
                            a1[mt][ks], bwk[nt], acc[mt][nt], 0, 0, 0);
            }

            // ---- epilogue1: relu, pack, write hT[dout][atom] ----
            #pragma unroll
            for (int mt = 0; mt < 2; ++mt)
                #pragma unroll
                for (int nt = 0; nt < 4; ++nt) {
                    short4s p;
                    p[0] = bf(fmaxf(acc[mt][nt][0], 0.f));
                    p[1] = bf(fmaxf(acc[mt][nt][1], 0.f));
                    p[2] = bf(fmaxf(acc[mt][nt][2], 0.f));
                    p[3] = bf(fmaxf(acc[mt][nt][3], 0.f));
                    *(short4s*)&xb[(nt * 16 + c) * AP + mt * 16 + 4 * g] = p;
                }
            __builtin_amdgcn_wave_barrier();

            // ---- GEMM2: u^T = h^T * B^T ----
            short8 b2[4];
            #pragma unroll
            for (int dt = 0; dt < 4; ++dt)
                b2[dt] = *(const short8*)&xb[(dt * 16 + c) * AP + 8 * g];
            f32x4 ua[4][2];
            #pragma unroll
            for (int dt = 0; dt < 4; ++dt)
                #pragma unroll
                for (int at = 0; at < 2; ++at) {
                    f32x4 z; z[0]=0.f; z[1]=0.f; z[2]=0.f; z[3]=0.f;
                    ua[dt][at] = __builtin_amdgcn_mfma_f32_16x16x32_bf16(
                        b2[dt], amat[at], z, 0, 0, 0);
                }

            // ---- per-atom norms (atom = at*16+c; reduce over g-groups) ----
            float ss0 = 0.f, ss1 = 0.f;
            #pragma unroll
            for (int dt = 0; dt < 4; ++dt)
                #pragma unroll
                for (int r = 0; r < 4; ++r) {
                    ss0 += ua[dt][0][r] * ua[dt][0][r];
                    ss1 += ua[dt][1][r] * ua[dt][1][r];
                }
            ss0 += __shfl_xor(ss0, 16); ss0 += __shfl_xor(ss0, 32);
            ss1 += __shfl_xor(ss1, 16); ss1 += __shfl_xor(ss1, 32);
            float rn0 = __builtin_amdgcn_rsqf(fmaxf(ss0, 1e-24f));
            float rn1 = __builtin_amdgcn_rsqf(fmaxf(ss1, 1e-24f));
            __builtin_amdgcn_wave_barrier();

            if (layer != LH - 1) {
                // ---- v' -> xb[atom][dim] (b2 already consumed into regs) ----
                #pragma unroll
                for (int at = 0; at < 2; ++at) {
                    float r0 = at ? rn1 : rn0;
                    #pragma unroll
                    for (int dt = 0; dt < 4; ++dt) {
                        short4s p;
                        p[0] = bf(ua[dt][at][0] * r0);
                        p[1] = bf(ua[dt][at][1] * r0);
                        p[2] = bf(ua[dt][at][2] * r0);
                        p[3] = bf(ua[dt][at][3] * r0);
                        *(short4s*)&xb[(at * 16 + c) * VP + dt * 16 + 4 * g] = p;
                    }
                }
                __builtin_amdgcn_wave_barrier();
                #pragma unroll
                for (int mt = 0; mt < 2; ++mt)
                    #pragma unroll
                    for (int ks = 0; ks < 2; ++ks)
                        a1[mt][ks] = *(const short8*)&xb[(mt * 16 + c) * VP + ks * 32 + 8 * g];
            } else {
                // ---- molecule sum via 15-shfl split-butterfly over c-lanes ----
                float mx[16];
                #pragma unroll
                for (int dt = 0; dt < 4; ++dt)
                    #pragma unroll
                    for (int r = 0; r < 4; ++r)
                        mx[dt * 4 + r] = ua[dt][0][r] * rn0 + ua[dt][1][r] * rn1;
                #pragma unroll
                for (int k = 0; k < 8; ++k) {
                    float send = (c & 8) ? mx[k] : mx[k + 8];
                    float keep = (c & 8) ? mx[k + 8] : mx[k];
                    mx[k] = keep + __shfl_xor(send, 8);
                }
                #pragma unroll
                for (int k = 0; k < 4; ++k) {
                    float send = (c & 4) ? mx[k] : mx[k + 4];
                    float keep = (c & 4) ? mx[k + 4] : mx[k];
                    mx[k] = keep + __shfl_xor(send, 4);
                }
                #pragma unroll
                for (int k = 0; k < 2; ++k) {
                    float send = (c & 2) ? mx[k] : mx[k + 2];
                    float keep = (c & 2) ? mx[k + 2] : mx[k];
                    mx[k] = keep + __shfl_xor(send, 2);
                }
                {
                    float send = (c & 1) ? mx[0] : mx[1];
                    float keep = (c & 1) ? mx[1] : mx[0];
                    mx[0] = keep + __shfl_xor(send, 1);
                }
                int dim = (c >> 2) * 16 + 4 * g + (c & 3);
                mv[dim] = mx[0];             // overlays hT region (done with it)
                __builtin_amdgcn_wave_barrier();
            }
        }

        // ---- output MLP (lane = dout), W_out rows L2-hot ----
        float cur = 0.f;
        for (int layer = 0; layer < LO; ++layer) {
            const float4* wr = (const float4*)(W_out + ((size_t)layer * DIM + l) * DIM);
            const float4* mv4 = (const float4*)mv;
            float accv = b_out[layer * DIM + l];
            #pragma unroll
            for (int k = 0; k < 16; ++k) {
                float4 vv = mv4[k]; float4 ww = wr[k];
                accv += vv.x * ww.x + vv.y * ww.y + vv.z * ww.z + vv.w * ww.w;
            }
            __builtin_amdgcn_wave_barrier();
            cur = fmaxf(accv, 0.f);
            mv[l] = cur;
            __builtin_amdgcn_wave_barrier();
        }
        float p = cur * W_prop[l];
        #pragma unroll
        for (int o = 32; o; o >>= 1) p += __shfl_xor(p, o);
        if (l == 0) out[mol] = p + b_prop[0];
        __builtin_amdgcn_wave_barrier();
    }
}

// ---------------- launch ----------------------------------------------------
extern "C" void kernel_launch(void* const* d_in, const int* in_sizes, int n_in,
                              void* d_out, int out_size, void* d_ws, size_t ws_size,
                              hipStream_t stream)
{
    const float* emb    = (const float*)d_in[0];
    const float* W_fp   = (const float*)d_in[1];
    const float* b_fp   = (const float*)d_in[2];
    const float* W_out  = (const float*)d_in[3];
    const float* b_out  = (const float*)d_in[4];
    const float* W_prop = (const float*)d_in[5];
    const float* b_prop = (const float*)d_in[6];
    const int*   fps    = (const int*)d_in[7];
    const int*   esrc   = (const int*)d_in[8];
    const int*   edst   = (const int*)d_in[9];

    const int T  = in_sizes[7];
    const int E  = in_sizes[8];
    const int NF = in_sizes[0] / DIM;
    const int LH = in_sizes[1] / (DIM * DIM);
    const int LO = in_sizes[3] / (DIM * DIM);
    const int M  = T / S_ATOMS;

    // fast layout: [byte hist M*800 | embT bf16 | wpk]; fallback: [nibble hist | wpk]
    size_t hist_fast = (size_t)M * 800;
    size_t embT_b    = (size_t)NF * DIM * 2;
    size_t wpk_b     = (size_t)LH * 512 * 16;
    size_t need_fast = hist_fast + 256 + embT_b + 256 + wpk_b + 4096;
    bool fast = ws_size >= need_fast;

    unsigned* Bg; short* embT; short* wpk; size_t hist_bytes;
    if (fast) {
        hist_bytes = hist_fast;
        Bg   = (unsigned*)d_ws;
        embT = (short*)((char*)d_ws + hist_fast + 256);
        wpk  = (short*)((char*)d_ws + hist_fast + 256 + embT_b + 256);
    } else {
        hist_bytes = ((size_t)M * 625 + 1) / 2;
        Bg   = (unsigned*)d_ws;
        embT = nullptr;
        wpk  = (short*)((char*)d_ws + ((hist_bytes + 255) & ~(size_t)255) + 256);
    }

    hipMemsetAsync(Bg, 0, hist_bytes + 16, stream);

    int workA = E; if (NF * 8 > workA) workA = NF * 8; if (LH * 512 > workA) workA = LH * 512;
    phaseA_k<<<(workA + 255) / 256, 256, 0, stream>>>(
        W_fp, emb, esrc, edst, Bg, wpk, embT, LH, E, NF, fast ? 1 : 0);

    int grid = (M + BWAVES * PM - 1) / (BWAVES * PM);
    if (fast)
        gnn_k<true><<<grid, BWAVES * 64, 0, stream>>>(emb, embT, b_fp, W_out, b_out,
            W_prop, b_prop, fps, Bg, wpk, (float*)d_out, LH, LO, M);
    else
        gnn_k<false><<<grid, BWAVES * 64, 0, stream>>>(emb, embT, b_fp, W_out, b_out,
            W_prop, b_prop, fps, Bg, wpk, (float*)d_out, LH, LO, M);
}

// Round 9
// 193.601 us; speedup vs baseline: 1.1962x; 1.0020x over previous
//
#include <hip/hip_runtime.h>
#include <hip/hip_bf16.h>
#include <stdint.h>

#define S_ATOMS 25
#define DIM 64
#define AP 40      // hT row stride (shorts): 80B rows
#define VP 72      // v' row stride (shorts): 144B rows
#define BWAVES 4   // waves per block (256 threads)
#define PM 2       // molecules per wave (sequential, 1 live at a time)
#define XB2 2560   // shorts per wave buffer: max(64*AP, 32*VP) = 2560 (5120B)

typedef __attribute__((ext_vector_type(8))) short short8;   // 8 bf16
typedef __attribute__((ext_vector_type(4))) short short4s;  // 4 bf16 (b64)
typedef __attribute__((ext_vector_type(4))) float f32x4;

static __device__ __forceinline__ short bf(float x) {
    return (short)__builtin_bit_cast(unsigned short, __float2bfloat16(x));
}

// ---------------- phase A: W-pack + emb->bf16 + edge histogram --------------
// byteMode: hist byte index n = mol*800 + dl*32 + sl  (row stride 32, pad=0)
// nibble  : hist nibble index n = mol*625 + dl*25 + sl
__global__ __launch_bounds__(256) void phaseA_k(
    const float* __restrict__ W_fp, const float* __restrict__ emb,
    const int* __restrict__ esrc, const int* __restrict__ edst,
    unsigned* __restrict__ Bg, short* __restrict__ wpk, short* __restrict__ embT,
    int LH, int E, int NF, int byteMode)
{
    int gid = blockIdx.x * 256 + threadIdx.x;
    if (gid < LH * 512) {             // prepack W_fp MFMA B-fragments
        int t = gid;
        int layer = t >> 9, q = t & 511;
        int nt = q >> 7, ks = (q >> 6) & 1, lane = q & 63;
        int cc = lane & 15, gg = lane >> 4;
        const float* p = W_fp + (size_t)layer * 4096 + (nt * 16 + cc) * 64 + ks * 32 + 8 * gg;
        short8 s;
        #pragma unroll
        for (int j = 0; j < 8; ++j) s[j] = bf(p[j]);
        *(short8*)(wpk + (size_t)t * 8) = s;
    }
    if (byteMode && gid < NF * 8) {   // emb f32 -> bf16 row-major
        int row = gid >> 3, seg = gid & 7;
        const float* p = emb + (size_t)row * DIM + seg * 8;
        short8 s;
        #pragma unroll
        for (int j = 0; j < 8; ++j) s[j] = bf(p[j]);
        *(short8*)(embT + (size_t)row * DIM + seg * 8) = s;
    }
    if (gid < E) {                    // adjacency histogram
        int s = esrc[gid], d = edst[gid];
        int m  = s / S_ATOMS;
        int sl = s - m * S_ATOMS;
        int dl = d - m * S_ATOMS;
        if (byteMode) {
            int n = m * 800 + dl * 32 + sl;          // byte index
            atomicAdd(&Bg[n >> 2], 1u << ((n & 3) * 8));
        } else {
            int n = m * 625 + dl * 25 + sl;          // nibble index
            atomicAdd(&Bg[n >> 3], 1u << ((n & 7) * 4));
        }
    }
}

// ---------------- fused per-molecule GNN: 4 waves/block, PM mols per wave ---
// GEMM1: h[atom][dout] = v*W^T (A=v, B=Wpack)       -> 16 MFMA
// GEMM2: u^T[dim][atom] = h^T * B^T = mfma(b2,amat) -> 8 MFMA,  B = I + A
template<bool FAST>
__global__ __launch_bounds__(256, 4) void gnn_k(
    const float* __restrict__ emb,     // [NF,64] f32 (fallback path)
    const short* __restrict__ embT,    // [NF,64] bf16 (fast path)
    const float* __restrict__ b_fp,    // [LH,64]
    const float* __restrict__ W_out,   // [LO,64,64]
    const float* __restrict__ b_out,   // [LO,64]
    const float* __restrict__ W_prop,  // [1,64]
    const float* __restrict__ b_prop,  // [1]
    const int*   __restrict__ fps,     // [T]
    const unsigned* __restrict__ Bg,   // adjacency counts (byte or nibble)
    const short* __restrict__ wpk,     // prepacked W frags
    float* __restrict__ out,           // [M]
    int LH, int LO, int M)
{
    __shared__ __align__(16) short xb_all[BWAVES][XB2];   // 20480 B total
    const int w = threadIdx.x >> 6, l = threadIdx.x & 63;
    const int c = l & 15, g = l >> 4;
    short* xb = xb_all[w];
    float* mv = (float*)xb;            // 64-float mol vector overlays xb
    const short8* wp8 = (const short8*)wpk;

    for (int mi = 0; mi < PM; ++mi) {
        const int mol = (blockIdx.x * BWAVES + w) * PM + mi;
        if (mol >= M) break;           // wave-uniform

        // ---- amat: B^T-operand frags, B = I + A ----
        short8 amat[2];
        #pragma unroll
        for (int at = 0; at < 2; ++at) {
            int row = at * 16 + c;
            float f[8];
            if (row < S_ATOMS) {
                if (FAST) {
                    // bytes [mol*800 + row*32 + 8g .. +7]: two aligned u32 words
                    int w0 = mol * 200 + row * 8 + g * 2;
                    unsigned u0 = Bg[w0], u1 = Bg[w0 + 1];
                    #pragma unroll
                    for (int j = 0; j < 8; ++j) {
                        unsigned u = (j < 4) ? u0 : u1;
                        float fj = (float)((u >> (8 * (j & 3))) & 0xffu);
                        if (8 * g + j == row) fj += 1.0f;              // +I
                        f[j] = fj;   // pad cols 25..31 never incremented -> 0
                    }
                } else {
                    int n0 = mol * 625 + row * 25 + 8 * g;
                    unsigned lo = Bg[n0 >> 3], hi = Bg[(n0 >> 3) + 1];
                    unsigned long long v64 = ((unsigned long long)hi << 32) | lo;
                    v64 >>= ((n0 & 7) * 4);
                    #pragma unroll
                    for (int j = 0; j < 8; ++j) {
                        unsigned n = (unsigned)(v64 >> (4 * j)) & 0xFu;
                        f[j] = (8 * g + j) < S_ATOMS ? (float)n : 0.f;
                        if (8 * g + j == row) f[j] += 1.0f;
                    }
                }
            } else {
                #pragma unroll
                for (int j = 0; j < 8; ++j) f[j] = 0.f;
            }
            short8 s;
            #pragma unroll
            for (int j = 0; j < 8; ++j) s[j] = bf(f[j]);
            amat[at] = s;
        }

        // ---- layer-0 A-frags from the embedding table ----
        short8 a1[2][2];
        #pragma unroll
        for (int mt = 0; mt < 2; ++mt) {
            int atom = mt * 16 + c;
            int aa = atom < S_ATOMS ? atom : S_ATOMS - 1;  // pads killed by B cols=0
            int fi = fps[mol * S_ATOMS + aa];
            #pragma unroll
            for (int ks = 0; ks < 2; ++ks) {
                if (FAST) {
                    a1[mt][ks] = *(const short8*)(embT + (size_t)fi * DIM + ks * 32 + 8 * g);
                } else {
                    const float4* qp = (const float4*)(emb + (size_t)fi * DIM + ks * 32 + 8 * g);
                    float4 f0 = qp[0], f1 = qp[1];
                    short8 s;
                    s[0]=bf(f0.x); s[1]=bf(f0.y); s[2]=bf(f0.z); s[3]=bf(f0.w);
                    s[4]=bf(f1.x); s[5]=bf(f1.y); s[6]=bf(f1.z); s[7]=bf(f1.w);
                    a1[mt][ks] = s;
                }
            }
        }

        for (int layer = 0; layer < LH; ++layer) {
            // ---- GEMM1: acc = v*W^T + b ----
            float bv[4];
            #pragma unroll
            for (int nt = 0; nt < 4; ++nt) bv[nt] = b_fp[layer * DIM + nt * 16 + c];
            f32x4 acc[2][4];
            #pragma unroll
            for (int mt = 0; mt < 2; ++mt)
                #pragma unroll
                for (int nt = 0; nt < 4; ++nt) {
                    f32x4 a; a[0]=bv[nt]; a[1]=bv[nt]; a[2]=bv[nt]; a[3]=bv[nt];
                    acc[mt][nt] = a;
                }
            #pragma unroll
            for (int ks = 0; ks < 2; ++ks) {
                short8 bwk[4];
                #pragma unroll
                for (int nt = 0; nt < 4; ++nt)
                    bwk[nt] = wp8[layer * 512 + nt * 128 + ks * 64 + l];
                __builtin_amdgcn_s_setprio(1);
                #pragma unroll
                for (int mt = 0; mt < 2; ++mt)
                    #pragma unroll
                    for (int nt = 0; nt < 4; ++nt)
                        acc[mt][nt] = __builtin_amdgcn_mfma_f32_16x16x32_bf16(
                            a1[mt][ks], bwk[nt], acc[mt][nt], 0, 0, 0);
                __builtin_amdgcn_s_setprio(0);
            }

            // ---- epilogue1: relu, pack, write hT[dout][atom] ----
            #pragma unroll
            for (int mt = 0; mt < 2; ++mt)
                #pragma unroll
                for (int nt = 0; nt < 4; ++nt) {
                    short4s p;
                    p[0] = bf(fmaxf(acc[mt][nt][0], 0.f));
                    p[1] = bf(fmaxf(acc[mt][nt][1], 0.f));
                    p[2] = bf(fmaxf(acc[mt][nt][2], 0.f));
                    p[3] = bf(fmaxf(acc[mt][nt][3], 0.f));
                    *(short4s*)&xb[(nt * 16 + c) * AP + mt * 16 + 4 * g] = p;
                }
            __builtin_amdgcn_wave_barrier();

            // ---- GEMM2: u^T = h^T * B^T ----
            short8 b2[4];
            #pragma unroll
            for (int dt = 0; dt < 4; ++dt)
                b2[dt] = *(const short8*)&xb[(dt * 16 + c) * AP + 8 * g];
            f32x4 ua[4][2];
            __builtin_amdgcn_s_setprio(1);
            #pragma unroll
            for (int dt = 0; dt < 4; ++dt)
                #pragma unroll
                for (int at = 0; at < 2; ++at) {
                    f32x4 z; z[0]=0.f; z[1]=0.f; z[2]=0.f; z[3]=0.f;
                    ua[dt][at] = __builtin_amdgcn_mfma_f32_16x16x32_bf16(
                        b2[dt], amat[at], z, 0, 0, 0);
                }
            __builtin_amdgcn_s_setprio(0);

            // ---- per-atom norms (atom = at*16+c; reduce over g-groups) ----
            float ss0 = 0.f, ss1 = 0.f;
            #pragma unroll
            for (int dt = 0; dt < 4; ++dt)
                #pragma unroll
                for (int r = 0; r < 4; ++r) {
                    ss0 += ua[dt][0][r] * ua[dt][0][r];
                    ss1 += ua[dt][1][r] * ua[dt][1][r];
                }
            ss0 += __shfl_xor(ss0, 16); ss0 += __shfl_xor(ss0, 32);
            ss1 += __shfl_xor(ss1, 16); ss1 += __shfl_xor(ss1, 32);
            float rn0 = __builtin_amdgcn_rsqf(fmaxf(ss0, 1e-24f));
            float rn1 = __builtin_amdgcn_rsqf(fmaxf(ss1, 1e-24f));
            __builtin_amdgcn_wave_barrier();

            if (layer != LH - 1) {
                // ---- v' -> xb[atom][dim] (b2 already consumed into regs) ----
                #pragma unroll
                for (int at = 0; at < 2; ++at) {
                    float r0 = at ? rn1 : rn0;
                    #pragma unroll
                    for (int dt = 0; dt < 4; ++dt) {
                        short4s p;
                        p[0] = bf(ua[dt][at][0] * r0);
                        p[1] = bf(ua[dt][at][1] * r0);
                        p[2] = bf(ua[dt][at][2] * r0);
                        p[3] = bf(ua[dt][at][3] * r0);
                        *(short4s*)&xb[(at * 16 + c) * VP + dt * 16 + 4 * g] = p;
                    }
                }
                __builtin_amdgcn_wave_barrier();
                #pragma unroll
                for (int mt = 0; mt < 2; ++mt)
                    #pragma unroll
                    for (int ks = 0; ks < 2; ++ks)
                        a1[mt][ks] = *(const short8*)&xb[(mt * 16 + c) * VP + ks * 32 + 8 * g];
            } else {
                // ---- molecule sum via 15-shfl split-butterfly over c-lanes ----
                float mx[16];
                #pragma unroll
                for (int dt = 0; dt < 4; ++dt)
                    #pragma unroll
                    for (int r = 0; r < 4; ++r)
                        mx[dt * 4 + r] = ua[dt][0][r] * rn0 + ua[dt][1][r] * rn1;
                #pragma unroll
                for (int k = 0; k < 8; ++k) {
                    float send = (c & 8) ? mx[k] : mx[k + 8];
                    float keep = (c & 8) ? mx[k + 8] : mx[k];
                    mx[k] = keep + __shfl_xor(send, 8);
                }
                #pragma unroll
                for (int k = 0; k < 4; ++k) {
                    float send = (c & 4) ? mx[k] : mx[k + 4];
                    float keep = (c & 4) ? mx[k + 4] : mx[k];
                    mx[k] = keep + __shfl_xor(send, 4);
                }
                #pragma unroll
                for (int k = 0; k < 2; ++k) {
                    float send = (c & 2) ? mx[k] : mx[k + 2];
                    float keep = (c & 2) ? mx[k + 2] : mx[k];
                    mx[k] = keep + __shfl_xor(send, 2);
                }
                {
                    float send = (c & 1) ? mx[0] : mx[1];
                    float keep = (c & 1) ? mx[1] : mx[0];
                    mx[0] = keep + __shfl_xor(send, 1);
                }
                int dim = (c >> 2) * 16 + 4 * g + (c & 3);
                mv[dim] = mx[0];             // overlays hT region (done with it)
                __builtin_amdgcn_wave_barrier();
            }
        }

        // ---- output MLP (lane = dout), W_out rows L2-hot ----
        float cur = 0.f;
        for (int layer = 0; layer < LO; ++layer) {
            const float4* wr = (const float4*)(W_out + ((size_t)layer * DIM + l) * DIM);
            const float4* mv4 = (const float4*)mv;
            float accv = b_out[layer * DIM + l];
            #pragma unroll
            for (int k = 0; k < 16; ++k) {
                float4 vv = mv4[k]; float4 ww = wr[k];
                accv += vv.x * ww.x + vv.y * ww.y + vv.z * ww.z + vv.w * ww.w;
            }
            __builtin_amdgcn_wave_barrier();
            cur = fmaxf(accv, 0.f);
            mv[l] = cur;
            __builtin_amdgcn_wave_barrier();
        }
        float p = cur * W_prop[l];
        #pragma unroll
        for (int o = 32; o; o >>= 1) p += __shfl_xor(p, o);
        if (l == 0) out[mol] = p + b_prop[0];
        __builtin_amdgcn_wave_barrier();
    }
}

// ---------------- launch ----------------------------------------------------
extern "C" void kernel_launch(void* const* d_in, const int* in_sizes, int n_in,
                              void* d_out, int out_size, void* d_ws, size_t ws_size,
                              hipStream_t stream)
{
    const float* emb    = (const float*)d_in[0];
    const float* W_fp   = (const float*)d_in[1];
    const float* b_fp   = (const float*)d_in[2];
    const float* W_out  = (const float*)d_in[3];
    const float* b_out  = (const float*)d_in[4];
    const float* W_prop = (const float*)d_in[5];
    const float* b_prop = (const float*)d_in[6];
    const int*   fps    = (const int*)d_in[7];
    const int*   esrc   = (const int*)d_in[8];
    const int*   edst   = (const int*)d_in[9];

    const int T  = in_sizes[7];
    const int E  = in_sizes[8];
    const int NF = in_sizes[0] / DIM;
    const int LH = in_sizes[1] / (DIM * DIM);
    const int LO = in_sizes[3] / (DIM * DIM);
    const int M  = T / S_ATOMS;

    // fast layout: [byte hist M*800 | embT bf16 | wpk]; fallback: [nibble hist | wpk]
    size_t hist_fast = (size_t)M * 800;
    size_t embT_b    = (size_t)NF * DIM * 2;
    size_t wpk_b     = (size_t)LH * 512 * 16;
    size_t need_fast = hist_fast + 256 + embT_b + 256 + wpk_b + 4096;
    bool fast = ws_size >= need_fast;

    unsigned* Bg; short* embT; short* wpk; size_t hist_bytes;
    if (fast) {
        hist_bytes = hist_fast;
        Bg   = (unsigned*)d_ws;
        embT = (short*)((char*)d_ws + hist_fast + 256);
        wpk  = (short*)((char*)d_ws + hist_fast + 256 + embT_b + 256);
    } else {
        hist_bytes = ((size_t)M * 625 + 1) / 2;
        Bg   = (unsigned*)d_ws;
        embT = nullptr;
        wpk  = (short*)((char*)d_ws + ((hist_bytes + 255) & ~(size_t)255) + 256);
    }

    hipMemsetAsync(Bg, 0, hist_bytes + 16, stream);

    int workA = E; if (NF * 8 > workA) workA = NF * 8; if (LH * 512 > workA) workA = LH * 512;
    phaseA_k<<<(workA + 255) / 256, 256, 0, stream>>>(
        W_fp, emb, esrc, edst, Bg, wpk, embT, LH, E, NF, fast ? 1 : 0);

    int grid = (M + BWAVES * PM - 1) / (BWAVES * PM);
    if (fast)
        gnn_k<true><<<grid, BWAVES * 64, 0, stream>>>(emb, embT, b_fp, W_out, b_out,
            W_prop, b_prop, fps, Bg, wpk, (float*)d_out, LH, LO, M);
    else
        gnn_k<false><<<grid, BWAVES * 64, 0, stream>>>(emb, embT, b_fp, W_out, b_out,
            W_prop, b_prop, fps, Bg, wpk, (float*)d_out, LH, LO, M);
}

// Round 10
// 161.453 us; speedup vs baseline: 1.4344x; 1.1991x over previous
//
#include <hip/hip_runtime.h>
#include <hip/hip_bf16.h>
#include <stdint.h>

#define S_ATOMS 25
#define DIM 64
#define AP 40      // hT row stride (shorts): 80B rows
#define VP 72      // v' row stride (shorts): 144B rows
#define WAVES 4    // waves per block (256 threads)
#define PM 2       // molecules per wave (sequential, 1 live at a time)
#define XB2 2560   // shorts per wave buffer: max(64*AP, 32*VP) = 2560 (5120B)

typedef __attribute__((ext_vector_type(8))) short short8;   // 8 bf16
typedef __attribute__((ext_vector_type(4))) short short4s;  // 4 bf16 (b64)
typedef __attribute__((ext_vector_type(4))) float f32x4;

static __device__ __forceinline__ short bf(float x) {
    return (short)__builtin_bit_cast(unsigned short, __float2bfloat16(x));
}

// ---------------- phase A: W-pack + emb->bf16 + nibble edge histogram -------
// nibble index n = mol*625 + dl*25 + sl ; counts Poisson(0.16) -> never >= 16
__global__ __launch_bounds__(256) void phaseA_k(
    const float* __restrict__ W_fp, const float* __restrict__ emb,
    const int* __restrict__ esrc, const int* __restrict__ edst,
    unsigned* __restrict__ Bg, short* __restrict__ wpk, short* __restrict__ embT,
    int LH, int E, int NF, int doEmb)
{
    int gid = blockIdx.x * 256 + threadIdx.x;
    if (gid < LH * 512) {             // prepack W_fp MFMA B-fragments
        int t = gid;
        int layer = t >> 9, q = t & 511;
        int nt = q >> 7, ks = (q >> 6) & 1, lane = q & 63;
        int cc = lane & 15, gg = lane >> 4;
        const float* p = W_fp + (size_t)layer * 4096 + (nt * 16 + cc) * 64 + ks * 32 + 8 * gg;
        short8 s;
        #pragma unroll
        for (int j = 0; j < 8; ++j) s[j] = bf(p[j]);
        *(short8*)(wpk + (size_t)t * 8) = s;
    }
    if (doEmb && gid < NF * 8) {      // emb f32 -> bf16 row-major
        int row = gid >> 3, seg = gid & 7;
        const float* p = emb + (size_t)row * DIM + seg * 8;
        short8 s;
        #pragma unroll
        for (int j = 0; j < 8; ++j) s[j] = bf(p[j]);
        *(short8*)(embT + (size_t)row * DIM + seg * 8) = s;
    }
    if (gid < E) {                    // adjacency histogram (nibble)
        int s = esrc[gid], d = edst[gid];
        int m  = s / S_ATOMS;
        int sl = s - m * S_ATOMS;
        int dl = d - m * S_ATOMS;
        int n = m * 625 + dl * 25 + sl;
        atomicAdd(&Bg[n >> 3], 1u << ((n & 7) * 4));
    }
}

// ---------------- fused per-molecule GNN (round-4 structure + embT) ---------
// One wave = PM molecules sequentially. c = lane&15, g = lane>>4.
// GEMM1: h[atom][dout] = v*W^T (A=v, B=Wpack)       -> 16 MFMA
// GEMM2: u^T[dim][atom] = h^T * B^T = mfma(b2,amat) -> 8 MFMA,  B = I + A
template<bool FAST>
__global__ __launch_bounds__(256, 4) void gnn_k(
    const float* __restrict__ emb,     // [NF,64] f32 (fallback path)
    const short* __restrict__ embT,    // [NF,64] bf16 (fast path)
    const float* __restrict__ b_fp,    // [LH,64]
    const float* __restrict__ W_out,   // [LO,64,64]
    const float* __restrict__ b_out,   // [LO,64]
    const float* __restrict__ W_prop,  // [1,64]
    const float* __restrict__ b_prop,  // [1]
    const int*   __restrict__ fps,     // [T]
    const unsigned* __restrict__ Bg,   // nibble adjacency counts
    const short* __restrict__ wpk,     // prepacked W frags
    float* __restrict__ out,           // [M]
    int LH, int LO, int M)
{
    __shared__ __align__(16) short xb_all[WAVES][XB2];
    __shared__ __align__(16) float mv_all[WAVES][PM][DIM];
    const int w = threadIdx.x >> 6, l = threadIdx.x & 63;
    const int c = l & 15, g = l >> 4;
    short* xb = xb_all[w];
    const short8* wp8 = (const short8*)wpk;
    const int wave_id = blockIdx.x * WAVES + w;

    for (int mi = 0; mi < PM; ++mi) {
        const int mol = wave_id * PM + mi;
        if (mol >= M) break;           // wave-uniform

        // ---- amat: B^T-operand frags, B = I + A, from nibble histogram ----
        short8 amat[2];
        #pragma unroll
        for (int at = 0; at < 2; ++at) {
            int row = at * 16 + c;
            float f[8];
            if (row < S_ATOMS) {
                int n0 = mol * 625 + row * 25 + 8 * g;
                unsigned lo = Bg[n0 >> 3], hi = Bg[(n0 >> 3) + 1];
                unsigned long long v64 = ((unsigned long long)hi << 32) | lo;
                v64 >>= ((n0 & 7) * 4);
                #pragma unroll
                for (int j = 0; j < 8; ++j) {
                    unsigned n = (unsigned)(v64 >> (4 * j)) & 0xFu;
                    f[j] = (8 * g + j) < S_ATOMS ? (float)n : 0.f;
                    if (8 * g + j == row) f[j] += 1.0f;   // +I
                }
            } else {
                #pragma unroll
                for (int j = 0; j < 8; ++j) f[j] = 0.f;
            }
            short8 s;
            #pragma unroll
            for (int j = 0; j < 8; ++j) s[j] = bf(f[j]);
            amat[at] = s;
        }

        // ---- layer-0 A-frags from the embedding table ----
        short8 a1[2][2];
        #pragma unroll
        for (int mt = 0; mt < 2; ++mt) {
            int atom = mt * 16 + c;
            int aa = atom < S_ATOMS ? atom : S_ATOMS - 1;  // pads killed by B cols=0
            int fi = fps[mol * S_ATOMS + aa];
            #pragma unroll
            for (int ks = 0; ks < 2; ++ks) {
                if (FAST) {
                    a1[mt][ks] = *(const short8*)(embT + (size_t)fi * DIM + ks * 32 + 8 * g);
                } else {
                    const float4* qp = (const float4*)(emb + (size_t)fi * DIM + ks * 32 + 8 * g);
                    float4 f0 = qp[0], f1 = qp[1];
                    short8 s;
                    s[0]=bf(f0.x); s[1]=bf(f0.y); s[2]=bf(f0.z); s[3]=bf(f0.w);
                    s[4]=bf(f1.x); s[5]=bf(f1.y); s[6]=bf(f1.z); s[7]=bf(f1.w);
                    a1[mt][ks] = s;
                }
            }
        }

        for (int layer = 0; layer < LH; ++layer) {
            // ---- GEMM1: acc = v*W^T + b ----
            float bv[4];
            #pragma unroll
            for (int nt = 0; nt < 4; ++nt) bv[nt] = b_fp[layer * DIM + nt * 16 + c];
            f32x4 acc[2][4];
            #pragma unroll
            for (int mt = 0; mt < 2; ++mt)
                #pragma unroll
                for (int nt = 0; nt < 4; ++nt) {
                    f32x4 a; a[0]=bv[nt]; a[1]=bv[nt]; a[2]=bv[nt]; a[3]=bv[nt];
                    acc[mt][nt] = a;
                }
            #pragma unroll
            for (int ks = 0; ks < 2; ++ks) {
                short8 bwk[4];
                #pragma unroll
                for (int nt = 0; nt < 4; ++nt)
                    bwk[nt] = wp8[layer * 512 + nt * 128 + ks * 64 + l];
                #pragma unroll
                for (int mt = 0; mt < 2; ++mt)
                    #pragma unroll
                    for (int nt = 0; nt < 4; ++nt)
                        acc[mt][nt] = __builtin_amdgcn_mfma_f32_16x16x32_bf16(
                            a1[mt][ks], bwk[nt], acc[mt][nt], 0, 0, 0);
            }

            // ---- epilogue1: relu, pack, write hT[dout][atom] ----
            #pragma unroll
            for (int mt = 0; mt < 2; ++mt)
                #pragma unroll
                for (int nt = 0; nt < 4; ++nt) {
                    short4s p;
                    p[0] = bf(fmaxf(acc[mt][nt][0], 0.f));
                    p[1] = bf(fmaxf(acc[mt][nt][1], 0.f));
                    p[2] = bf(fmaxf(acc[mt][nt][2], 0.f));
                    p[3] = bf(fmaxf(acc[mt][nt][3], 0.f));
                    *(short4s*)&xb[(nt * 16 + c) * AP + mt * 16 + 4 * g] = p;
                }
            __builtin_amdgcn_wave_barrier();

            // ---- GEMM2: u^T = h^T * B^T ----
            short8 b2[4];
            #pragma unroll
            for (int dt = 0; dt < 4; ++dt)
                b2[dt] = *(const short8*)&xb[(dt * 16 + c) * AP + 8 * g];
            f32x4 ua[4][2];
            #pragma unroll
            for (int dt = 0; dt < 4; ++dt)
                #pragma unroll
                for (int at = 0; at < 2; ++at) {
                    f32x4 z; z[0]=0.f; z[1]=0.f; z[2]=0.f; z[3]=0.f;
                    ua[dt][at] = __builtin_amdgcn_mfma_f32_16x16x32_bf16(
                        b2[dt], amat[at], z, 0, 0, 0);
                }

            // ---- per-atom norms (atom = at*16+c; reduce over g-groups) ----
            float ss0 = 0.f, ss1 = 0.f;
            #pragma unroll
            for (int dt = 0; dt < 4; ++dt)
                #pragma unroll
                for (int r = 0; r < 4; ++r) {
                    ss0 += ua[dt][0][r] * ua[dt][0][r];
                    ss1 += ua[dt][1][r] * ua[dt][1][r];
                }
            ss0 += __shfl_xor(ss0, 16); ss0 += __shfl_xor(ss0, 32);
            ss1 += __shfl_xor(ss1, 16); ss1 += __shfl_xor(ss1, 32);
            float rn0 = __builtin_amdgcn_rsqf(fmaxf(ss0, 1e-24f));
            float rn1 = __builtin_amdgcn_rsqf(fmaxf(ss1, 1e-24f));

            bool lastl = (layer == LH - 1);
            __builtin_amdgcn_wave_barrier();
            if (!lastl) {
                // ---- v' -> xb[atom][dim] (b2 already consumed into regs) ----
                #pragma unroll
                for (int at = 0; at < 2; ++at) {
                    float r0 = at ? rn1 : rn0;
                    #pragma unroll
                    for (int dt = 0; dt < 4; ++dt) {
                        short4s p;
                        p[0] = bf(ua[dt][at][0] * r0);
                        p[1] = bf(ua[dt][at][1] * r0);
                        p[2] = bf(ua[dt][at][2] * r0);
                        p[3] = bf(ua[dt][at][3] * r0);
                        *(short4s*)&xb[(at * 16 + c) * VP + dt * 16 + 4 * g] = p;
                    }
                }
                __builtin_amdgcn_wave_barrier();
                #pragma unroll
                for (int mt = 0; mt < 2; ++mt)
                    #pragma unroll
                    for (int ks = 0; ks < 2; ++ks)
                        a1[mt][ks] = *(const short8*)&xb[(mt * 16 + c) * VP + ks * 32 + 8 * g];
            } else {
                // ---- molecule sum (round-4 style: 4-shfl tree per value) ----
                float mx[16];
                #pragma unroll
                for (int dt = 0; dt < 4; ++dt)
                    #pragma unroll
                    for (int r = 0; r < 4; ++r)
                        mx[dt * 4 + r] = ua[dt][0][r] * rn0 + ua[dt][1][r] * rn1;
                #pragma unroll
                for (int t = 0; t < 16; ++t) {
                    mx[t] += __shfl_xor(mx[t], 1);
                    mx[t] += __shfl_xor(mx[t], 2);
                    mx[t] += __shfl_xor(mx[t], 4);
                    mx[t] += __shfl_xor(mx[t], 8);
                }
                if (c == 0) {
                    #pragma unroll
                    for (int dt = 0; dt < 4; ++dt)
                        #pragma unroll
                        for (int r = 0; r < 4; ++r)
                            mv_all[w][mi][dt * 16 + 4 * g + r] = mx[dt * 4 + r];
                }
                __builtin_amdgcn_wave_barrier();
            }
        }
    }

    // ---- output MLP, batched for both molecules (lane = dout) ----
    float cur[PM];
    for (int layer = 0; layer < LO; ++layer) {
        const float4* wr = (const float4*)(W_out + ((size_t)layer * DIM + l) * DIM);
        float bb = b_out[layer * DIM + l];
        float av[PM];
        #pragma unroll
        for (int q = 0; q < PM; ++q) av[q] = bb;
        #pragma unroll
        for (int k = 0; k < 16; ++k) {
            float4 ww = wr[k];
            #pragma unroll
            for (int q = 0; q < PM; ++q) {
                float4 vv = ((const float4*)mv_all[w][q])[k];
                av[q] += vv.x * ww.x + vv.y * ww.y + vv.z * ww.z + vv.w * ww.w;
            }
        }
        __builtin_amdgcn_wave_barrier();
        #pragma unroll
        for (int q = 0; q < PM; ++q) { cur[q] = fmaxf(av[q], 0.f); mv_all[w][q][l] = cur[q]; }
        __builtin_amdgcn_wave_barrier();
    }
    float wpv = W_prop[l], bp = b_prop[0];
    #pragma unroll
    for (int q = 0; q < PM; ++q) {
        float p = cur[q] * wpv;
        p += __shfl_xor(p, 1);  p += __shfl_xor(p, 2);
        p += __shfl_xor(p, 4);  p += __shfl_xor(p, 8);
        p += __shfl_xor(p, 16); p += __shfl_xor(p, 32);
        int mol = wave_id * PM + q;
        if (l == 0 && mol < M) out[mol] = p + bp;
    }
}

// ---------------- launch ----------------------------------------------------
extern "C" void kernel_launch(void* const* d_in, const int* in_sizes, int n_in,
                              void* d_out, int out_size, void* d_ws, size_t ws_size,
                              hipStream_t stream)
{
    const float* emb    = (const float*)d_in[0];
    const float* W_fp   = (const float*)d_in[1];
    const float* b_fp   = (const float*)d_in[2];
    const float* W_out  = (const float*)d_in[3];
    const float* b_out  = (const float*)d_in[4];
    const float* W_prop = (const float*)d_in[5];
    const float* b_prop = (const float*)d_in[6];
    const int*   fps    = (const int*)d_in[7];
    const int*   esrc   = (const int*)d_in[8];
    const int*   edst   = (const int*)d_in[9];

    const int T  = in_sizes[7];
    const int E  = in_sizes[8];
    const int NF = in_sizes[0] / DIM;
    const int LH = in_sizes[1] / (DIM * DIM);
    const int LO = in_sizes[3] / (DIM * DIM);
    const int M  = T / S_ATOMS;

    // layout: [nibble hist | embT bf16 (fast) | wpk]
    size_t hist_bytes = (((size_t)M * 625 + 1) / 2 + 255) & ~(size_t)255;  // 6.25 MB
    size_t embT_b     = (size_t)NF * DIM * 2;
    size_t wpk_b      = (size_t)LH * 512 * 16;
    bool fast = ws_size >= hist_bytes + 256 + embT_b + 256 + wpk_b + 4096;

    unsigned* Bg  = (unsigned*)d_ws;
    short* embT; short* wpk;
    if (fast) {
        embT = (short*)((char*)d_ws + hist_bytes + 256);
        wpk  = (short*)((char*)d_ws + hist_bytes + 256 + embT_b + 256);
    } else {
        embT = nullptr;
        wpk  = (short*)((char*)d_ws + hist_bytes + 256);
    }

    hipMemsetAsync(Bg, 0, hist_bytes + 16, stream);

    int workA = E; if (fast && NF * 8 > workA) workA = NF * 8; if (LH * 512 > workA) workA = LH * 512;
    phaseA_k<<<(workA + 255) / 256, 256, 0, stream>>>(
        W_fp, emb, esrc, edst, Bg, wpk, embT, LH, E, NF, fast ? 1 : 0);

    int grid = (M + WAVES * PM - 1) / (WAVES * PM);
    if (fast)
        gnn_k<true><<<grid, WAVES * 64, 0, stream>>>(emb, embT, b_fp, W_out, b_out,
            W_prop, b_prop, fps, Bg, wpk, (float*)d_out, LH, LO, M);
    else
        gnn_k<false><<<grid, WAVES * 64, 0, stream>>>(emb, embT, b_fp, W_out, b_out,
            W_prop, b_prop, fps, Bg, wpk, (float*)d_out, LH, LO, M);
}

// Round 11
// 157.574 us; speedup vs baseline: 1.4697x; 1.0246x over previous
//
#include <hip/hip_runtime.h>
#include <hip/hip_bf16.h>
#include <stdint.h>

#define S_ATOMS 25
#define DIM 64
#define AP 40      // hT row stride (shorts): 80B rows
#define VP 72      // v' row stride (shorts): 144B rows
#define WAVES 4    // waves per block (256 threads)
#define PM 2       // molecules per wave (sequential, 1 live at a time)
#define XB2 2560   // shorts per wave buffer: max(64*AP, 32*VP) = 2560 (5120B)

typedef __attribute__((ext_vector_type(8))) short short8;   // 8 bf16
typedef __attribute__((ext_vector_type(4))) short short4s;  // 4 bf16 (b64)
typedef __attribute__((ext_vector_type(4))) float f32x4;
typedef __attribute__((ext_vector_type(4))) unsigned uint4v;

static __device__ __forceinline__ short bf(float x) {
    return (short)__builtin_bit_cast(unsigned short, __float2bfloat16(x));
}

// ---------------- prep_k: zero hist + W-pack + emb->bf16 --------------------
__global__ __launch_bounds__(256) void prep_k(
    const float* __restrict__ W_fp, const float* __restrict__ emb,
    unsigned* __restrict__ Bg, short* __restrict__ wpk, short* __restrict__ embT,
    int LH, int NF, int nzero, int doEmb)
{
    int gid = blockIdx.x * 256 + threadIdx.x;
    if (gid < nzero) {                // zero the nibble histogram (16B/thread)
        uint4v z; z[0]=0; z[1]=0; z[2]=0; z[3]=0;
        ((uint4v*)Bg)[gid] = z;
    }
    if (gid < LH * 512) {             // prepack W_fp MFMA B-fragments
        int t = gid;
        int layer = t >> 9, q = t & 511;
        int nt = q >> 7, ks = (q >> 6) & 1, lane = q & 63;
        int cc = lane & 15, gg = lane >> 4;
        const float* p = W_fp + (size_t)layer * 4096 + (nt * 16 + cc) * 64 + ks * 32 + 8 * gg;
        short8 s;
        #pragma unroll
        for (int j = 0; j < 8; ++j) s[j] = bf(p[j]);
        *(short8*)(wpk + (size_t)t * 8) = s;
    }
    if (doEmb && gid < NF * 8) {      // emb f32 -> bf16 row-major
        int row = gid >> 3, seg = gid & 7;
        const float* p = emb + (size_t)row * DIM + seg * 8;
        short8 s;
        #pragma unroll
        for (int j = 0; j < 8; ++j) s[j] = bf(p[j]);
        *(short8*)(embT + (size_t)row * DIM + seg * 8) = s;
    }
}

// ---------------- ehist_k: nibble adjacency histogram, 4 edges/thread -------
// nibble index n = mol*625 + dl*25 + sl ; counts Poisson(0.16) -> never >= 16
__global__ __launch_bounds__(256) void ehist_k(
    const int* __restrict__ esrc, const int* __restrict__ edst,
    unsigned* __restrict__ Bg, int E)
{
    int t = blockIdx.x * 256 + threadIdx.x;
    int base = t * 4;
    if (base >= E) return;
    if (base + 4 <= E) {
        int4 s4 = ((const int4*)esrc)[t];
        int4 d4 = ((const int4*)edst)[t];
        int ss[4] = {s4.x, s4.y, s4.z, s4.w};
        int dd[4] = {d4.x, d4.y, d4.z, d4.w};
        #pragma unroll
        for (int j = 0; j < 4; ++j) {
            int m  = ss[j] / S_ATOMS;
            int sl = ss[j] - m * S_ATOMS;
            int dl = dd[j] - m * S_ATOMS;
            int n = m * 625 + dl * 25 + sl;
            atomicAdd(&Bg[n >> 3], 1u << ((n & 7) * 4));
        }
    } else {
        for (int e = base; e < E; ++e) {
            int s = esrc[e], d = edst[e];
            int m  = s / S_ATOMS;
            int sl = s - m * S_ATOMS;
            int dl = d - m * S_ATOMS;
            int n = m * 625 + dl * 25 + sl;
            atomicAdd(&Bg[n >> 3], 1u << ((n & 7) * 4));
        }
    }
}

// ---------------- fused per-molecule GNN (round-10 + butterfly molsum) ------
// One wave = PM molecules sequentially. c = lane&15, g = lane>>4.
// GEMM1: h[atom][dout] = v*W^T (A=v, B=Wpack)       -> 16 MFMA
// GEMM2: u^T[dim][atom] = h^T * B^T = mfma(b2,amat) -> 8 MFMA,  B = I + A
template<bool FAST>
__global__ __launch_bounds__(256, 4) void gnn_k(
    const float* __restrict__ emb,     // [NF,64] f32 (fallback path)
    const short* __restrict__ embT,    // [NF,64] bf16 (fast path)
    const float* __restrict__ b_fp,    // [LH,64]
    const float* __restrict__ W_out,   // [LO,64,64]
    const float* __restrict__ b_out,   // [LO,64]
    const float* __restrict__ W_prop,  // [1,64]
    const float* __restrict__ b_prop,  // [1]
    const int*   __restrict__ fps,     // [T]
    const unsigned* __restrict__ Bg,   // nibble adjacency counts
    const short* __restrict__ wpk,     // prepacked W frags
    float* __restrict__ out,           // [M]
    int LH, int LO, int M)
{
    __shared__ __align__(16) short xb_all[WAVES][XB2];
    __shared__ __align__(16) float mv_all[WAVES][PM][DIM];
    const int w = threadIdx.x >> 6, l = threadIdx.x & 63;
    const int c = l & 15, g = l >> 4;
    short* xb = xb_all[w];
    const short8* wp8 = (const short8*)wpk;
    const int wave_id = blockIdx.x * WAVES + w;

    for (int mi = 0; mi < PM; ++mi) {
        const int mol = wave_id * PM + mi;
        if (mol >= M) break;           // wave-uniform

        // ---- amat: B^T-operand frags, B = I + A, from nibble histogram ----
        short8 amat[2];
        #pragma unroll
        for (int at = 0; at < 2; ++at) {
            int row = at * 16 + c;
            float f[8];
            if (row < S_ATOMS) {
                int n0 = mol * 625 + row * 25 + 8 * g;
                unsigned lo = Bg[n0 >> 3], hi = Bg[(n0 >> 3) + 1];
                unsigned long long v64 = ((unsigned long long)hi << 32) | lo;
                v64 >>= ((n0 & 7) * 4);
                #pragma unroll
                for (int j = 0; j < 8; ++j) {
                    unsigned n = (unsigned)(v64 >> (4 * j)) & 0xFu;
                    f[j] = (8 * g + j) < S_ATOMS ? (float)n : 0.f;
                    if (8 * g + j == row) f[j] += 1.0f;   // +I
                }
            } else {
                #pragma unroll
                for (int j = 0; j < 8; ++j) f[j] = 0.f;
            }
            short8 s;
            #pragma unroll
            for (int j = 0; j < 8; ++j) s[j] = bf(f[j]);
            amat[at] = s;
        }

        // ---- layer-0 A-frags from the embedding table ----
        short8 a1[2][2];
        #pragma unroll
        for (int mt = 0; mt < 2; ++mt) {
            int atom = mt * 16 + c;
            int aa = atom < S_ATOMS ? atom : S_ATOMS - 1;  // pads killed by B cols=0
            int fi = fps[mol * S_ATOMS + aa];
            #pragma unroll
            for (int ks = 0; ks < 2; ++ks) {
                if (FAST) {
                    a1[mt][ks] = *(const short8*)(embT + (size_t)fi * DIM + ks * 32 + 8 * g);
                } else {
                    const float4* qp = (const float4*)(emb + (size_t)fi * DIM + ks * 32 + 8 * g);
                    float4 f0 = qp[0], f1 = qp[1];
                    short8 s;
                    s[0]=bf(f0.x); s[1]=bf(f0.y); s[2]=bf(f0.z); s[3]=bf(f0.w);
                    s[4]=bf(f1.x); s[5]=bf(f1.y); s[6]=bf(f1.z); s[7]=bf(f1.w);
                    a1[mt][ks] = s;
                }
            }
        }

        for (int layer = 0; layer < LH; ++layer) {
            // ---- GEMM1: acc = v*W^T + b ----
            float bv[4];
            #pragma unroll
            for (int nt = 0; nt < 4; ++nt) bv[nt] = b_fp[layer * DIM + nt * 16 + c];
            f32x4 acc[2][4];
            #pragma unroll
            for (int mt = 0; mt < 2; ++mt)
                #pragma unroll
                for (int nt = 0; nt < 4; ++nt) {
                    f32x4 a; a[0]=bv[nt]; a[1]=bv[nt]; a[2]=bv[nt]; a[3]=bv[nt];
                    acc[mt][nt] = a;
                }
            #pragma unroll
            for (int ks = 0; ks < 2; ++ks) {
                short8 bwk[4];
                #pragma unroll
                for (int nt = 0; nt < 4; ++nt)
                    bwk[nt] = wp8[layer * 512 + nt * 128 + ks * 64 + l];
                #pragma unroll
                for (int mt = 0; mt < 2; ++mt)
                    #pragma unroll
                    for (int nt = 0; nt < 4; ++nt)
                        acc[mt][nt] = __builtin_amdgcn_mfma_f32_16x16x32_bf16(
                            a1[mt][ks], bwk[nt], acc[mt][nt], 0, 0, 0);
            }

            // ---- epilogue1: relu, pack, write hT[dout][atom] ----
            #pragma unroll
            for (int mt = 0; mt < 2; ++mt)
                #pragma unroll
                for (int nt = 0; nt < 4; ++nt) {
                    short4s p;
                    p[0] = bf(fmaxf(acc[mt][nt][0], 0.f));
                    p[1] = bf(fmaxf(acc[mt][nt][1], 0.f));
                    p[2] = bf(fmaxf(acc[mt][nt][2], 0.f));
                    p[3] = bf(fmaxf(acc[mt][nt][3], 0.f));
                    *(short4s*)&xb[(nt * 16 + c) * AP + mt * 16 + 4 * g] = p;
                }
            __builtin_amdgcn_wave_barrier();

            // ---- GEMM2: u^T = h^T * B^T ----
            short8 b2[4];
            #pragma unroll
            for (int dt = 0; dt < 4; ++dt)
                b2[dt] = *(const short8*)&xb[(dt * 16 + c) * AP + 8 * g];
            f32x4 ua[4][2];
            #pragma unroll
            for (int dt = 0; dt < 4; ++dt)
                #pragma unroll
                for (int at = 0; at < 2; ++at) {
                    f32x4 z; z[0]=0.f; z[1]=0.f; z[2]=0.f; z[3]=0.f;
                    ua[dt][at] = __builtin_amdgcn_mfma_f32_16x16x32_bf16(
                        b2[dt], amat[at], z, 0, 0, 0);
                }

            // ---- per-atom norms (atom = at*16+c; reduce over g-groups) ----
            float ss0 = 0.f, ss1 = 0.f;
            #pragma unroll
            for (int dt = 0; dt < 4; ++dt)
                #pragma unroll
                for (int r = 0; r < 4; ++r) {
                    ss0 += ua[dt][0][r] * ua[dt][0][r];
                    ss1 += ua[dt][1][r] * ua[dt][1][r];
                }
            ss0 += __shfl_xor(ss0, 16); ss0 += __shfl_xor(ss0, 32);
            ss1 += __shfl_xor(ss1, 16); ss1 += __shfl_xor(ss1, 32);
            float rn0 = __builtin_amdgcn_rsqf(fmaxf(ss0, 1e-24f));
            float rn1 = __builtin_amdgcn_rsqf(fmaxf(ss1, 1e-24f));

            bool lastl = (layer == LH - 1);
            __builtin_amdgcn_wave_barrier();
            if (!lastl) {
                // ---- v' -> xb[atom][dim] (b2 already consumed into regs) ----
                #pragma unroll
                for (int at = 0; at < 2; ++at) {
                    float r0 = at ? rn1 : rn0;
                    #pragma unroll
                    for (int dt = 0; dt < 4; ++dt) {
                        short4s p;
                        p[0] = bf(ua[dt][at][0] * r0);
                        p[1] = bf(ua[dt][at][1] * r0);
                        p[2] = bf(ua[dt][at][2] * r0);
                        p[3] = bf(ua[dt][at][3] * r0);
                        *(short4s*)&xb[(at * 16 + c) * VP + dt * 16 + 4 * g] = p;
                    }
                }
                __builtin_amdgcn_wave_barrier();
                #pragma unroll
                for (int mt = 0; mt < 2; ++mt)
                    #pragma unroll
                    for (int ks = 0; ks < 2; ++ks)
                        a1[mt][ks] = *(const short8*)&xb[(mt * 16 + c) * VP + ks * 32 + 8 * g];
            } else {
                // ---- molecule sum via 15-shfl split-butterfly over c-lanes ----
                float mx[16];
                #pragma unroll
                for (int dt = 0; dt < 4; ++dt)
                    #pragma unroll
                    for (int r = 0; r < 4; ++r)
                        mx[dt * 4 + r] = ua[dt][0][r] * rn0 + ua[dt][1][r] * rn1;
                #pragma unroll
                for (int k = 0; k < 8; ++k) {
                    float send = (c & 8) ? mx[k] : mx[k + 8];
                    float keep = (c & 8) ? mx[k + 8] : mx[k];
                    mx[k] = keep + __shfl_xor(send, 8);
                }
                #pragma unroll
                for (int k = 0; k < 4; ++k) {
                    float send = (c & 4) ? mx[k] : mx[k + 4];
                    float keep = (c & 4) ? mx[k + 4] : mx[k];
                    mx[k] = keep + __shfl_xor(send, 4);
                }
                #pragma unroll
                for (int k = 0; k < 2; ++k) {
                    float send = (c & 2) ? mx[k] : mx[k + 2];
                    float keep = (c & 2) ? mx[k + 2] : mx[k];
                    mx[k] = keep + __shfl_xor(send, 2);
                }
                {
                    float send = (c & 1) ? mx[0] : mx[1];
                    float keep = (c & 1) ? mx[1] : mx[0];
                    mx[0] = keep + __shfl_xor(send, 1);
                }
                int dim = (c >> 2) * 16 + 4 * g + (c & 3);
                mv_all[w][mi][dim] = mx[0];
                __builtin_amdgcn_wave_barrier();
            }
        }
    }

    // ---- output MLP, batched for both molecules (lane = dout) ----
    float cur[PM];
    for (int layer = 0; layer < LO; ++layer) {
        const float4* wr = (const float4*)(W_out + ((size_t)layer * DIM + l) * DIM);
        float bb = b_out[layer * DIM + l];
        float av[PM];
        #pragma unroll
        for (int q = 0; q < PM; ++q) av[q] = bb;
        #pragma unroll
        for (int k = 0; k < 16; ++k) {
            float4 ww = wr[k];
            #pragma unroll
            for (int q = 0; q < PM; ++q) {
                float4 vv = ((const float4*)mv_all[w][q])[k];
                av[q] += vv.x * ww.x + vv.y * ww.y + vv.z * ww.z + vv.w * ww.w;
            }
        }
        __builtin_amdgcn_wave_barrier();
        #pragma unroll
        for (int q = 0; q < PM; ++q) { cur[q] = fmaxf(av[q], 0.f); mv_all[w][q][l] = cur[q]; }
        __builtin_amdgcn_wave_barrier();
    }
    float wpv = W_prop[l], bp = b_prop[0];
    #pragma unroll
    for (int q = 0; q < PM; ++q) {
        float p = cur[q] * wpv;
        p += __shfl_xor(p, 1);  p += __shfl_xor(p, 2);
        p += __shfl_xor(p, 4);  p += __shfl_xor(p, 8);
        p += __shfl_xor(p, 16); p += __shfl_xor(p, 32);
        int mol = wave_id * PM + q;
        if (l == 0 && mol < M) out[mol] = p + bp;
    }
}

// ---------------- launch ----------------------------------------------------
extern "C" void kernel_launch(void* const* d_in, const int* in_sizes, int n_in,
                              void* d_out, int out_size, void* d_ws, size_t ws_size,
                              hipStream_t stream)
{
    const float* emb    = (const float*)d_in[0];
    const float* W_fp   = (const float*)d_in[1];
    const float* b_fp   = (const float*)d_in[2];
    const float* W_out  = (const float*)d_in[3];
    const float* b_out  = (const float*)d_in[4];
    const float* W_prop = (const float*)d_in[5];
    const float* b_prop = (const float*)d_in[6];
    const int*   fps    = (const int*)d_in[7];
    const int*   esrc   = (const int*)d_in[8];
    const int*   edst   = (const int*)d_in[9];

    const int T  = in_sizes[7];
    const int E  = in_sizes[8];
    const int NF = in_sizes[0] / DIM;
    const int LH = in_sizes[1] / (DIM * DIM);
    const int LO = in_sizes[3] / (DIM * DIM);
    const int M  = T / S_ATOMS;

    // layout: [nibble hist | embT bf16 (fast) | wpk]
    size_t hist_bytes = (((size_t)M * 625 + 1) / 2 + 255) & ~(size_t)255;  // ~6.25 MB
    size_t embT_b     = (size_t)NF * DIM * 2;
    size_t wpk_b      = (size_t)LH * 512 * 16;
    bool fast = ws_size >= hist_bytes + 256 + embT_b + 256 + wpk_b + 4096;

    unsigned* Bg  = (unsigned*)d_ws;
    short* embT; short* wpk;
    if (fast) {
        embT = (short*)((char*)d_ws + hist_bytes + 256);
        wpk  = (short*)((char*)d_ws + hist_bytes + 256 + embT_b + 256);
    } else {
        embT = nullptr;
        wpk  = (short*)((char*)d_ws + hist_bytes + 256);
    }

    // prep: zero hist (vectorized) + pack W + convert emb  (replaces memset node)
    int nzero = (int)((hist_bytes + 16) / 16);
    int workP = nzero;
    if (fast && NF * 8 > workP) workP = NF * 8;
    if (LH * 512 > workP) workP = LH * 512;
    prep_k<<<(workP + 255) / 256, 256, 0, stream>>>(
        W_fp, emb, Bg, wpk, embT, LH, NF, nzero, fast ? 1 : 0);

    // edge histogram: 4 edges per thread
    int nthr = (E + 3) / 4;
    ehist_k<<<(nthr + 255) / 256, 256, 0, stream>>>(esrc, edst, Bg, E);

    int grid = (M + WAVES * PM - 1) / (WAVES * PM);
    if (fast)
        gnn_k<true><<<grid, WAVES * 64, 0, stream>>>(emb, embT, b_fp, W_out, b_out,
            W_prop, b_prop, fps, Bg, wpk, (float*)d_out, LH, LO, M);
    else
        gnn_k<false><<<grid, WAVES * 64, 0, stream>>>(emb, embT, b_fp, W_out, b_out,
            W_prop, b_prop, fps, Bg, wpk, (float*)d_out, LH, LO, M);
}